// Round 9
// baseline (887.954 us; speedup 1.0000x reference)
//
#include <hip/hip_runtime.h>

typedef unsigned int u32;

static inline int idiv_up(int a, int b) { return (a + b - 1) / b; }

#define BSHIFT 11          // bucket width 2048 nodes
#define BW     2048
#define ACHUNK 8192        // edges per binA block

// ---------------- bf16 pack/unpack ----------------

__device__ __forceinline__ u32 pack_bf16_rne(float lo, float hi) {
    u32 ul = __float_as_uint(lo);
    u32 uh = __float_as_uint(hi);
    ul = (ul + 0x7fffu + ((ul >> 16) & 1u)) >> 16;
    uh = (uh + 0x7fffu + ((uh >> 16) & 1u));
    return (ul & 0xffffu) | (uh & 0xffff0000u);
}
__device__ __forceinline__ float bf16_lo(u32 u) { return __uint_as_float(u << 16); }
__device__ __forceinline__ float bf16_hi(u32 u) { return __uint_as_float(u & 0xffff0000u); }

// ---------------- degree histogram (int) ----------------

__global__ __launch_bounds__(256) void count_deg_kernel(
    const int* __restrict__ colL, const int* __restrict__ colN,
    int eL, int eN,
    int* __restrict__ degL, int* __restrict__ degN)
{
    int i = blockIdx.x * 256 + threadIdx.x;
    if (i < eL) atomicAdd(&degL[colL[i]], 1);
    if (i < eN) atomicAdd(&degN[colN[i]], 1);
}

__global__ __launch_bounds__(256) void dinv_kernel(
    const int* __restrict__ degL, const int* __restrict__ degN,
    float* __restrict__ dinvL, float* __restrict__ dinvN, int n)
{
    int i = blockIdx.x * 256 + threadIdx.x;
    if (i < n) {
        dinvL[i] = rsqrtf((float)degL[i] + 1.0f);   // +1 self loop
        dinvN[i] = rsqrtf((float)degN[i] + 1.0f);
    }
}

// ---------------- exclusive scan -> rowptr ----------------

__global__ __launch_bounds__(1024) void scan_kernel(
    const int* __restrict__ degL, const int* __restrict__ degN, int n,
    int* __restrict__ rowptrL, int* __restrict__ rowptrN)
{
    const int* deg = blockIdx.x ? degN : degL;
    int* rowptr    = blockIdx.x ? rowptrN : rowptrL;

    __shared__ int ls[1024];
    const int t = threadIdx.x;
    const int chunk = (n + 1023) / 1024;
    const int base = t * chunk;

    int s = 0;
    for (int i = 0; i < chunk; ++i) {
        int idx = base + i;
        if (idx < n) s += deg[idx];
    }
    ls[t] = s;
    __syncthreads();
    for (int off = 1; off < 1024; off <<= 1) {
        int add = (t >= off) ? ls[t - off] : 0;
        __syncthreads();
        ls[t] += add;
        __syncthreads();
    }
    int running = (t == 0) ? 0 : ls[t - 1];
    int total = ls[1023];
    for (int i = 0; i < chunk; ++i) {
        int idx = base + i;
        if (idx < n) {
            rowptr[idx] = running;
            running += deg[idx];
        }
    }
    if (t == 1023) rowptr[n] = total;
}

// ---------------- bucket cursor init: gcur[b] = rowptr[b*BW] ----------------

__global__ void init_gcur_kernel(
    const int* __restrict__ rowptrL, const int* __restrict__ rowptrN,
    int* __restrict__ gcurL, int* __restrict__ gcurN, int nb)
{
    int t = threadIdx.x;
    if (t < nb) {
        gcurL[t] = rowptrL[t << BSHIFT];
        gcurN[t] = rowptrN[t << BSHIFT];
    }
}

// ---------------- radix pass A: bin edges by dest-bucket ----------------

__global__ __launch_bounds__(256) void binA_kernel(
    const int* __restrict__ rowL, const int* __restrict__ colL, int eL,
    const int* __restrict__ rowN, const int* __restrict__ colN, int eN,
    int* __restrict__ gcurL, int* __restrict__ gcurN,
    uint2* __restrict__ stagedL, uint2* __restrict__ stagedN, int nb)
{
    const int adj = blockIdx.y;
    const int* rowA = adj ? rowN : rowL;
    const int* colA = adj ? colN : colL;
    const int e     = adj ? eN   : eL;
    int* gcur       = adj ? gcurN : gcurL;
    uint2* staged   = adj ? stagedN : stagedL;

    __shared__ int hist[64];
    __shared__ int base[64];
    const int t = threadIdx.x;
    if (t < 64) hist[t] = 0;
    __syncthreads();

    const int i0 = blockIdx.x * ACHUNK;
    const int i1 = min(i0 + ACHUNK, e);

    for (int i = i0 + t; i < i1; i += 256)
        atomicAdd(&hist[colA[i] >> BSHIFT], 1);
    __syncthreads();

    if (t < 64) {
        int cnt = hist[t];
        if (t < nb && cnt > 0) base[t] = atomicAdd(&gcur[t], cnt);
    }
    __syncthreads();
    if (t < 64) hist[t] = 0;    // reuse as per-bucket offset
    __syncthreads();

    for (int i = i0 + t; i < i1; i += 256) {
        int c = colA[i], r = rowA[i];
        int b = c >> BSHIFT;
        int pos = base[b] + atomicAdd(&hist[b], 1);
        staged[pos] = make_uint2((u32)c, (u32)r);
    }
}

// ---------------- radix pass B: place within bucket (LDS cursors) ----------------

__global__ __launch_bounds__(256) void binB_kernel(
    const int* __restrict__ rowptrL, const int* __restrict__ rowptrN,
    const uint2* __restrict__ stagedL, const uint2* __restrict__ stagedN,
    int* __restrict__ csrL, int* __restrict__ csrN, int n)
{
    const int adj = blockIdx.y;
    const int* rowptr   = adj ? rowptrN : rowptrL;
    const uint2* staged = adj ? stagedN : stagedL;
    int* csr            = adj ? csrN    : csrL;

    __shared__ int lcur[BW];
    const int lo = blockIdx.x << BSHIFT;
    const int hi = min(lo + BW, n);
    const int t = threadIdx.x;

    for (int i = lo + t; i < hi; i += 256) lcur[i - lo] = rowptr[i];
    __syncthreads();

    const int s0 = rowptr[lo], s1 = rowptr[hi];
    for (int i = s0 + t; i < s1; i += 256) {
        uint2 er = staged[i];
        int p = atomicAdd(&lcur[(int)er.x - lo], 1);
        csr[p] = (int)er.y;
    }
}

// ---------------- GEMM: y(bf16) = (A @ W) * dinv[row] ----------------

template<int NC>
__global__ __launch_bounds__(256) void gemm_kernel(
    const float* __restrict__ A, int n,
    const float* __restrict__ Wa, const float* __restrict__ Wb,
    const float* __restrict__ dinva, const float* __restrict__ dinvb,
    u32* __restrict__ ya, u32* __restrict__ yb,
    const float* __restrict__ bn_scale, const float* __restrict__ bn_shift)
{
    constexpr int K   = 128;
    constexpr int TR  = 64;        // rows per block
    constexpr int CG  = NC / 4;    // float4 column groups
    constexpr int TY  = 256 / CG;  // thread-row groups
    constexpr int RPT = TR / TY;   // rows per thread

    __shared__ float xs[TR][K];

    const float* W    = blockIdx.y ? Wb    : Wa;
    const float* dinv = blockIdx.y ? dinvb : dinva;
    u32* y            = blockIdx.y ? yb    : ya;

    const int row0 = blockIdx.x * TR;
    const int t = threadIdx.x;

    const float4* A4 = (const float4*)A;
    #pragma unroll
    for (int i = 0; i < (TR * (K / 4)) / 256; ++i) {
        int fl = i * 256 + t;
        int r  = fl >> 5;       // K/4 == 32
        int c4 = fl & 31;
        float4 v = make_float4(0.f, 0.f, 0.f, 0.f);
        int rr = row0 + r;
        if (rr < n) v = A4[(size_t)rr * 32 + c4];
        if (bn_scale) {
            float4 sc = ((const float4*)bn_scale)[c4];
            float4 sh = ((const float4*)bn_shift)[c4];
            v.x = fmaxf(v.x * sc.x + sh.x, 0.f);
            v.y = fmaxf(v.y * sc.y + sh.y, 0.f);
            v.z = fmaxf(v.z * sc.z + sh.z, 0.f);
            v.w = fmaxf(v.w * sc.w + sh.w, 0.f);
        }
        *(float4*)&xs[r][c4 * 4] = v;
    }
    __syncthreads();

    const int cg = t % CG;
    const int ty = t / CG;

    float4 accv[RPT];
    #pragma unroll
    for (int r = 0; r < RPT; ++r) accv[r] = make_float4(0.f, 0.f, 0.f, 0.f);

    const float4* W4 = (const float4*)W;
    for (int k = 0; k < K; k += 4) {
        float4 w0 = W4[(size_t)(k + 0) * CG + cg];
        float4 w1 = W4[(size_t)(k + 1) * CG + cg];
        float4 w2 = W4[(size_t)(k + 2) * CG + cg];
        float4 w3 = W4[(size_t)(k + 3) * CG + cg];
        #pragma unroll
        for (int r = 0; r < RPT; ++r) {
            float4 a = *(const float4*)&xs[ty * RPT + r][k];
            accv[r].x += a.x * w0.x; accv[r].y += a.x * w0.y; accv[r].z += a.x * w0.z; accv[r].w += a.x * w0.w;
            accv[r].x += a.y * w1.x; accv[r].y += a.y * w1.y; accv[r].z += a.y * w1.z; accv[r].w += a.y * w1.w;
            accv[r].x += a.z * w2.x; accv[r].y += a.z * w2.y; accv[r].z += a.z * w2.z; accv[r].w += a.z * w2.w;
            accv[r].x += a.w * w3.x; accv[r].y += a.w * w3.y; accv[r].z += a.w * w3.z; accv[r].w += a.w * w3.w;
        }
    }

    #pragma unroll
    for (int r = 0; r < RPT; ++r) {
        int rr = row0 + ty * RPT + r;
        if (rr < n) {
            float dv = dinv[rr];
            float4 o = accv[r];
            o.x *= dv; o.y *= dv; o.z *= dv; o.w *= dv;
            uint2 pk;
            pk.x = pack_bf16_rne(o.x, o.y);
            pk.y = pack_bf16_rne(o.z, o.w);
            ((uint2*)y)[(size_t)rr * CG + cg] = pk;
        }
    }
}

// ---------------- fused gather + combine (+bias, BN stats) ----------------
// Dual-stream: L and N adjacency pipelines interleaved in one loop -> up to
// 16 independent row loads in flight per wave. For CH=128 a wave owns one
// node, so csr offsets are wave-uniform: readfirstlane forces scalar (s_load)
// index fetches off the vector-memory path.

template<int CH, bool STATS>
__global__ __launch_bounds__(256) void gather_kernel(
    const int* __restrict__ rowptrL, const int* __restrict__ csrL,
    const int* __restrict__ rowptrN, const int* __restrict__ csrN,
    const u32* __restrict__ yL, const u32* __restrict__ yN,
    const float* __restrict__ dinvL, const float* __restrict__ dinvN,
    const float* __restrict__ bL, const float* __restrict__ bN,
    float* __restrict__ out, int n,
    float* __restrict__ bn_sum, float* __restrict__ bn_sumsq)
{
    constexpr int CHW = CH / 2;         // u32 lanes per node
    constexpr int NPB = 256 / CHW;      // nodes per block-iteration
    const int c  = threadIdx.x % CHW;
    const int ns = threadIdx.x / CHW;
    const float2 blv = ((const float2*)bL)[c];
    const float2 bnv = ((const float2*)bN)[c];
    const float cb0 = blv.x + 0.5f * bnv.x;
    const float cb1 = blv.y + 0.5f * bnv.y;

    float s0 = 0.f, s1 = 0.f, q0 = 0.f, q1 = 0.f;

    for (int node0 = blockIdx.x * NPB; node0 < n; node0 += gridDim.x * NPB) {
        const int node = node0 + ns;
        const bool valid = node < n;
        const int nodec = valid ? node : 0;

        u32 selfL = yL[(size_t)nodec * CHW + c];
        u32 selfN = yN[(size_t)nodec * CHW + c];
        float sL0 = bf16_lo(selfL), sL1 = bf16_hi(selfL);
        float sN0 = bf16_lo(selfN), sN1 = bf16_hi(selfN);

        int jL = rowptrL[nodec], eL2 = rowptrL[nodec + 1];
        int jN = rowptrN[nodec], eN2 = rowptrN[nodec + 1];
        if (!valid) { eL2 = jL; eN2 = jN; }
        if constexpr (CHW == 64) {   // wave-uniform -> scalarize
            jL  = __builtin_amdgcn_readfirstlane(jL);
            eL2 = __builtin_amdgcn_readfirstlane(eL2);
            jN  = __builtin_amdgcn_readfirstlane(jN);
            eN2 = __builtin_amdgcn_readfirstlane(eN2);
        }
        const int lenL = eL2 - jL;
        const int lenN = eN2 - jN;

        int idxL[8], idxN[8];
        if (lenL > 0) {
            #pragma unroll
            for (int k = 0; k < 8; ++k) idxL[k] = csrL[jL + min(k, lenL - 1)];
        }
        if (lenN > 0) {
            #pragma unroll
            for (int k = 0; k < 8; ++k) idxN[k] = csrN[jN + min(k, lenN - 1)];
        }

        const int mx = max(lenL, lenN);
        for (int base = 0; base < mx; base += 8) {
            const bool doL = base < lenL;
            const bool doN = base < lenN;
            u32 aL[8], aN[8];
            if (doL) {
                #pragma unroll
                for (int k = 0; k < 8; ++k) aL[k] = yL[(size_t)idxL[k] * CHW + c];
            }
            if (doN) {
                #pragma unroll
                for (int k = 0; k < 8; ++k) aN[k] = yN[(size_t)idxN[k] * CHW + c];
            }
            if (doL && base + 8 < lenL) {
                #pragma unroll
                for (int k = 0; k < 8; ++k) idxL[k] = csrL[jL + min(base + 8 + k, lenL - 1)];
            }
            if (doN && base + 8 < lenN) {
                #pragma unroll
                for (int k = 0; k < 8; ++k) idxN[k] = csrN[jN + min(base + 8 + k, lenN - 1)];
            }
            if (doL) {
                #pragma unroll
                for (int k = 0; k < 8; ++k) {
                    float m = (base + k < lenL) ? 1.0f : 0.0f;
                    sL0 = fmaf(m, bf16_lo(aL[k]), sL0);
                    sL1 = fmaf(m, bf16_hi(aL[k]), sL1);
                }
            }
            if (doN) {
                #pragma unroll
                for (int k = 0; k < 8; ++k) {
                    float m = (base + k < lenN) ? 1.0f : 0.0f;
                    sN0 = fmaf(m, bf16_lo(aN[k]), sN0);
                    sN1 = fmaf(m, bf16_hi(aN[k]), sN1);
                }
            }
        }

        if (valid) {
            float dl = dinvL[node], dn = 0.5f * dinvN[node];
            float v0 = dl * sL0 + dn * sN0 + cb0;
            float v1 = dl * sL1 + dn * sN1 + cb1;
            ((float2*)out)[(size_t)node * CHW + c] = make_float2(v0, v1);
            if constexpr (STATS) { s0 += v0; s1 += v1; q0 += v0 * v0; q1 += v1 * v1; }
        }
    }

    if constexpr (STATS) {
        __shared__ float4 ls[256];
        ls[threadIdx.x] = make_float4(s0, s1, q0, q1);
        __syncthreads();
        if (threadIdx.x < CHW) {
            float4 a = ls[threadIdx.x];
            #pragma unroll
            for (int i = 1; i < NPB; ++i) {
                float4 b = ls[threadIdx.x + i * CHW];
                a.x += b.x; a.y += b.y; a.z += b.z; a.w += b.w;
            }
            atomicAdd(&bn_sum[2 * threadIdx.x + 0], a.x);
            atomicAdd(&bn_sum[2 * threadIdx.x + 1], a.y);
            atomicAdd(&bn_sumsq[2 * threadIdx.x + 0], a.z);
            atomicAdd(&bn_sumsq[2 * threadIdx.x + 1], a.w);
        }
    }
}

__global__ void bn_final_kernel(
    const float* __restrict__ sum, const float* __restrict__ sumsq,
    const float* __restrict__ gamma, const float* __restrict__ beta,
    float* __restrict__ scale, float* __restrict__ shift, float inv_n)
{
    int c = threadIdx.x;
    float mean = sum[c] * inv_n;
    float var  = sumsq[c] * inv_n - mean * mean;
    float sc = gamma[c] * rsqrtf(var + 1e-5f);
    scale[c] = sc;
    shift[c] = beta[c] - mean * sc;
}

// ---------------- launch ----------------

extern "C" void kernel_launch(void* const* d_in, const int* in_sizes, int n_in,
                              void* d_out, int out_size, void* d_ws, size_t ws_size,
                              hipStream_t stream)
{
    const float* x     = (const float*)d_in[0];
    const int*   adjL  = (const int*)d_in[1];   // adj_low
    const int*   adjN  = (const int*)d_in[3];   // adj_nd_low (adj_high/nd_high unused)
    const float* W1L   = (const float*)d_in[5];
    const float* b1L   = (const float*)d_in[6];
    const float* W1N   = (const float*)d_in[7];
    const float* b1N   = (const float*)d_in[8];
    const float* gamma = (const float*)d_in[9];
    const float* beta  = (const float*)d_in[10];
    const float* W2L   = (const float*)d_in[11];
    const float* b2L   = (const float*)d_in[12];
    const float* W2N   = (const float*)d_in[13];
    const float* b2N   = (const float*)d_in[14];

    const int n  = in_sizes[0] / 128;
    const int eL = in_sizes[1] / 2;
    const int eN = in_sizes[3] / 2;
    const int* rowL = adjL;  const int* colL = adjL + eL;
    const int* rowN = adjN;  const int* colN = adjN + eN;
    const int nb = idiv_up(n, BW);

    char* p = (char*)d_ws;
    const size_t ybytes = (size_t)n * 128 * sizeof(short);   // bf16 [n][128]
    u32* y1L = (u32*)p; p += ybytes;
    u32* y1N = (u32*)p; p += ybytes;
    float* h = (float*)p; p += (size_t)n * 128 * sizeof(float);
    float* dinvL = (float*)p; p += (size_t)n * sizeof(float);
    float* dinvN = (float*)p; p += (size_t)n * sizeof(float);
    float* bn_sum   = (float*)p; p += 128 * sizeof(float);
    float* bn_sumsq = (float*)p; p += 128 * sizeof(float);
    float* bn_scale = (float*)p; p += 128 * sizeof(float);
    float* bn_shift = (float*)p; p += 128 * sizeof(float);
    int* degL    = (int*)p; p += (size_t)n * sizeof(int);
    int* degN    = (int*)p; p += (size_t)n * sizeof(int);
    int* rowptrL = (int*)p; p += (size_t)(n + 1) * sizeof(int);
    int* rowptrN = (int*)p; p += (size_t)(n + 1) * sizeof(int);
    int* gcurL   = (int*)p; p += 64 * sizeof(int);
    int* gcurN   = (int*)p; p += 64 * sizeof(int);
    int* csrL    = (int*)p; p += (size_t)eL * sizeof(int);
    int* csrN    = (int*)p; p += (size_t)eN * sizeof(int);

    // staging aliases h (h is dead until gather1, which runs after binB)
    uint2* stagedL = (uint2*)h;
    uint2* stagedN = stagedL + eL;

    // layer-2 y tables ([n][64] bf16 each) reuse y1L space (exactly fits)
    u32* y2L = y1L;
    u32* y2N = y1L + (size_t)n * 32;

    hipMemsetAsync(degL, 0, (size_t)n * 2 * sizeof(int), stream);
    hipMemsetAsync(bn_sum, 0, 2 * 128 * sizeof(float), stream);

    const int emax = eL > eN ? eL : eN;
    count_deg_kernel<<<idiv_up(emax, 256), 256, 0, stream>>>(colL, colN, eL, eN, degL, degN);
    dinv_kernel<<<idiv_up(n, 256), 256, 0, stream>>>(degL, degN, dinvL, dinvN, n);
    scan_kernel<<<2, 1024, 0, stream>>>(degL, degN, n, rowptrL, rowptrN);
    init_gcur_kernel<<<1, 64, 0, stream>>>(rowptrL, rowptrN, gcurL, gcurN, nb);

    binA_kernel<<<dim3(idiv_up(emax, ACHUNK), 2), 256, 0, stream>>>(
        rowL, colL, eL, rowN, colN, eN, gcurL, gcurN, stagedL, stagedN, nb);
    binB_kernel<<<dim3(nb, 2), 256, 0, stream>>>(
        rowptrL, rowptrN, stagedL, stagedN, csrL, csrN, n);

    // layer 1
    gemm_kernel<128><<<dim3(idiv_up(n, 64), 2), 256, 0, stream>>>(
        x, n, W1L, W1N, dinvL, dinvN, y1L, y1N, nullptr, nullptr);

    gather_kernel<128, true><<<4096, 256, 0, stream>>>(
        rowptrL, csrL, rowptrN, csrN, y1L, y1N, dinvL, dinvN,
        b1L, b1N, h, n, bn_sum, bn_sumsq);

    bn_final_kernel<<<1, 128, 0, stream>>>(bn_sum, bn_sumsq, gamma, beta,
                                           bn_scale, bn_shift, 1.0f / (float)n);

    // layer 2 (BN+ReLU fused into GEMM A-load)
    gemm_kernel<64><<<dim3(idiv_up(n, 64), 2), 256, 0, stream>>>(
        h, n, W2L, W2N, dinvL, dinvN, y2L, y2N, bn_scale, bn_shift);

    gather_kernel<64, false><<<4096, 256, 0, stream>>>(
        rowptrL, csrL, rowptrN, csrN, y2L, y2N, dinvL, dinvN,
        b2L, b2N, (float*)d_out, n, nullptr, nullptr);
}

// Round 10
// 800.870 us; speedup vs baseline: 1.1087x; 1.1087x over previous
//
#include <hip/hip_runtime.h>

typedef unsigned int u32;
typedef unsigned short u16;
using bf16x8 = __attribute__((ext_vector_type(8))) short;
using f32x4  = __attribute__((ext_vector_type(4))) float;

static inline int idiv_up(int a, int b) { return (a + b - 1) / b; }

#define BSHIFT 11          // bucket width 2048 nodes
#define BW     2048
#define ACHUNK 8192        // edges per binA block

// ---------------- bf16 pack/unpack ----------------

__device__ __forceinline__ u32 pack_bf16_rne(float lo, float hi) {
    u32 ul = __float_as_uint(lo);
    u32 uh = __float_as_uint(hi);
    ul = (ul + 0x7fffu + ((ul >> 16) & 1u)) >> 16;
    uh = (uh + 0x7fffu + ((uh >> 16) & 1u));
    return (ul & 0xffffu) | (uh & 0xffff0000u);
}
__device__ __forceinline__ u16 bf16_rne1(float v) {
    u32 u = __float_as_uint(v);
    return (u16)((u + 0x7fffu + ((u >> 16) & 1u)) >> 16);
}
__device__ __forceinline__ float bf16_lo(u32 u) { return __uint_as_float(u << 16); }
__device__ __forceinline__ float bf16_hi(u32 u) { return __uint_as_float(u & 0xffff0000u); }

// ---------------- degree histogram (int) ----------------

__global__ __launch_bounds__(256) void count_deg_kernel(
    const int* __restrict__ colL, const int* __restrict__ colN,
    int eL, int eN,
    int* __restrict__ degL, int* __restrict__ degN)
{
    int i = blockIdx.x * 256 + threadIdx.x;
    if (i < eL) atomicAdd(&degL[colL[i]], 1);
    if (i < eN) atomicAdd(&degN[colN[i]], 1);
}

__global__ __launch_bounds__(256) void dinv_kernel(
    const int* __restrict__ degL, const int* __restrict__ degN,
    float* __restrict__ dinvL, float* __restrict__ dinvN, int n)
{
    int i = blockIdx.x * 256 + threadIdx.x;
    if (i < n) {
        dinvL[i] = rsqrtf((float)degL[i] + 1.0f);   // +1 self loop
        dinvN[i] = rsqrtf((float)degN[i] + 1.0f);
    }
}

// ---------------- exclusive scan -> rowptr ----------------

__global__ __launch_bounds__(1024) void scan_kernel(
    const int* __restrict__ degL, const int* __restrict__ degN, int n,
    int* __restrict__ rowptrL, int* __restrict__ rowptrN)
{
    const int* deg = blockIdx.x ? degN : degL;
    int* rowptr    = blockIdx.x ? rowptrN : rowptrL;

    __shared__ int ls[1024];
    const int t = threadIdx.x;
    const int chunk = (n + 1023) / 1024;
    const int base = t * chunk;

    int s = 0;
    for (int i = 0; i < chunk; ++i) {
        int idx = base + i;
        if (idx < n) s += deg[idx];
    }
    ls[t] = s;
    __syncthreads();
    for (int off = 1; off < 1024; off <<= 1) {
        int add = (t >= off) ? ls[t - off] : 0;
        __syncthreads();
        ls[t] += add;
        __syncthreads();
    }
    int running = (t == 0) ? 0 : ls[t - 1];
    int total = ls[1023];
    for (int i = 0; i < chunk; ++i) {
        int idx = base + i;
        if (idx < n) {
            rowptr[idx] = running;
            running += deg[idx];
        }
    }
    if (t == 1023) rowptr[n] = total;
}

// ---------------- bucket cursor init ----------------

__global__ void init_gcur_kernel(
    const int* __restrict__ rowptrL, const int* __restrict__ rowptrN,
    int* __restrict__ gcurL, int* __restrict__ gcurN, int nb)
{
    int t = threadIdx.x;
    if (t < nb) {
        gcurL[t] = rowptrL[t << BSHIFT];
        gcurN[t] = rowptrN[t << BSHIFT];
    }
}

// ---------------- radix pass A ----------------

__global__ __launch_bounds__(256) void binA_kernel(
    const int* __restrict__ rowL, const int* __restrict__ colL, int eL,
    const int* __restrict__ rowN, const int* __restrict__ colN, int eN,
    int* __restrict__ gcurL, int* __restrict__ gcurN,
    uint2* __restrict__ stagedL, uint2* __restrict__ stagedN, int nb)
{
    const int adj = blockIdx.y;
    const int* rowA = adj ? rowN : rowL;
    const int* colA = adj ? colN : colL;
    const int e     = adj ? eN   : eL;
    int* gcur       = adj ? gcurN : gcurL;
    uint2* staged   = adj ? stagedN : stagedL;

    __shared__ int hist[64];
    __shared__ int base[64];
    const int t = threadIdx.x;
    if (t < 64) hist[t] = 0;
    __syncthreads();

    const int i0 = blockIdx.x * ACHUNK;
    const int i1 = min(i0 + ACHUNK, e);

    for (int i = i0 + t; i < i1; i += 256)
        atomicAdd(&hist[colA[i] >> BSHIFT], 1);
    __syncthreads();

    if (t < 64) {
        int cnt = hist[t];
        if (t < nb && cnt > 0) base[t] = atomicAdd(&gcur[t], cnt);
    }
    __syncthreads();
    if (t < 64) hist[t] = 0;
    __syncthreads();

    for (int i = i0 + t; i < i1; i += 256) {
        int c = colA[i], r = rowA[i];
        int b = c >> BSHIFT;
        int pos = base[b] + atomicAdd(&hist[b], 1);
        staged[pos] = make_uint2((u32)c, (u32)r);
    }
}

// ---------------- radix pass B ----------------

__global__ __launch_bounds__(256) void binB_kernel(
    const int* __restrict__ rowptrL, const int* __restrict__ rowptrN,
    const uint2* __restrict__ stagedL, const uint2* __restrict__ stagedN,
    int* __restrict__ csrL, int* __restrict__ csrN, int n)
{
    const int adj = blockIdx.y;
    const int* rowptr   = adj ? rowptrN : rowptrL;
    const uint2* staged = adj ? stagedN : stagedL;
    int* csr            = adj ? csrN    : csrL;

    __shared__ int lcur[BW];
    const int lo = blockIdx.x << BSHIFT;
    const int hi = min(lo + BW, n);
    const int t = threadIdx.x;

    for (int i = lo + t; i < hi; i += 256) lcur[i - lo] = rowptr[i];
    __syncthreads();

    const int s0 = rowptr[lo], s1 = rowptr[hi];
    for (int i = s0 + t; i < s1; i += 256) {
        uint2 er = staged[i];
        int p = atomicAdd(&lcur[(int)er.x - lo], 1);
        csr[p] = (int)er.y;
    }
}

// ---------------- W prep: fp32 [K][NC] -> bf16 W^T [NC][128] ----------------

__global__ __launch_bounds__(256) void wprep_kernel(
    const float* __restrict__ W1L, const float* __restrict__ W1N,
    const float* __restrict__ W2L, const float* __restrict__ W2N,
    u16* __restrict__ T1L, u16* __restrict__ T1N,
    u16* __restrict__ T2L, u16* __restrict__ T2N)
{
    const int which = blockIdx.y;
    const float* src = which == 0 ? W1L : which == 1 ? W1N : which == 2 ? W2L : W2N;
    u16* dst         = which == 0 ? T1L : which == 1 ? T1N : which == 2 ? T2L : T2N;
    const int nc = which < 2 ? 128 : 64;

    int i = blockIdx.x * 256 + threadIdx.x;
    if (i < 128 * nc) {
        int k = i / nc, nn = i % nc;
        dst[nn * 128 + k] = bf16_rne1(src[i]);
    }
}

// ---------------- MFMA GEMM: y(bf16) = (A @ W) * dinv[row] ------------------
// A fp32 [n][128] (optional BN+ReLU on load), Wt bf16 [NCH][128] (pre-
// transposed). Feeds Wt as MFMA A-operand, x as B-operand so D rows = output
// channels: lane holds 4 consecutive channels of one node -> in-lane bf16
// pack. Block = 64 nodes x both streams; A staged once to LDS (bf16,
// XOR-swizzled byte^=(r&7)<<4 vs 16-way ds_read_b128 conflict).
// mfma_f32_16x16x32_bf16: C/D col=lane&15 row=(lane>>4)*4+reg [verified];
// A row=lane&15 k=(lane>>4)*8+e; B col=lane&15 k=(lane>>4)*8+e.

template<int NCH, bool BN>
__global__ __launch_bounds__(256) void mfma_gemm_kernel(
    const float* __restrict__ A, int n,
    const u16* __restrict__ WtL, const u16* __restrict__ WtN,
    const float* __restrict__ dinvL, const float* __restrict__ dinvN,
    u32* __restrict__ yL, u32* __restrict__ yN,
    const float* __restrict__ bn_scale, const float* __restrict__ bn_shift)
{
    constexpr int NT = (NCH == 128) ? 4 : 2;   // node tiles per wave
    __shared__ u16 lsa[64 * 128];

    const int row0 = blockIdx.x * 64;
    const int t = threadIdx.x;
    const int l = t & 63;
    const int w = t >> 6;

    // ---- stage A tile: fp32 -> bf16 LDS, swizzled ----
    const float4* A4 = (const float4*)A;
    #pragma unroll
    for (int i = 0; i < 8; ++i) {
        int q = i * 256 + t;
        int r = q >> 5, c4 = q & 31;
        int rr = row0 + r;
        float4 v = make_float4(0.f, 0.f, 0.f, 0.f);
        if (rr < n) v = A4[(size_t)rr * 32 + c4];
        if constexpr (BN) {
            float4 sc = ((const float4*)bn_scale)[c4];
            float4 sh = ((const float4*)bn_shift)[c4];
            v.x = fmaxf(v.x * sc.x + sh.x, 0.f);
            v.y = fmaxf(v.y * sc.y + sh.y, 0.f);
            v.z = fmaxf(v.z * sc.z + sh.z, 0.f);
            v.w = fmaxf(v.w * sc.w + sh.w, 0.f);
        }
        int byte = (r * 256 + c4 * 8) ^ ((r & 7) << 4);
        *(uint2*)((char*)lsa + byte) = make_uint2(pack_bf16_rne(v.x, v.y),
                                                 pack_bf16_rne(v.z, v.w));
    }
    __syncthreads();

    const int stream = w >> 1;
    const int chbase  = (NCH == 128) ? (w & 1) * 64 : 0;
    const int nodebase = (NCH == 128) ? 0 : (w & 1) * 32;
    const u16* Wt      = stream ? WtN : WtL;
    const float* dinv  = stream ? dinvN : dinvL;
    u32* y             = stream ? yN : yL;

    f32x4 acc[4][NT];
    #pragma unroll
    for (int ct = 0; ct < 4; ++ct)
        #pragma unroll
        for (int nt = 0; nt < NT; ++nt)
            acc[ct][nt] = (f32x4){0.f, 0.f, 0.f, 0.f};

    const int lm = l & 15;
    const int lq = l >> 4;

    #pragma unroll
    for (int ks = 0; ks < 4; ++ks) {
        const int k0 = ks * 32 + lq * 8;
        bf16x8 wf[4];
        #pragma unroll
        for (int ct = 0; ct < 4; ++ct) {
            int nch = chbase + ct * 16 + lm;
            wf[ct] = *(const bf16x8*)&Wt[(size_t)nch * 128 + k0];
        }
        #pragma unroll
        for (int nt = 0; nt < NT; ++nt) {
            int m = nodebase + nt * 16 + lm;
            int byte = (m * 256 + k0 * 2) ^ ((m & 7) << 4);
            bf16x8 xf = *(const bf16x8*)((const char*)lsa + byte);
            #pragma unroll
            for (int ct = 0; ct < 4; ++ct)
                acc[ct][nt] = __builtin_amdgcn_mfma_f32_16x16x32_bf16(
                    wf[ct], xf, acc[ct][nt], 0, 0, 0);
        }
    }

    // ---- epilogue: *dinv, pack bf16, store uint2 ----
    #pragma unroll
    for (int nt = 0; nt < NT; ++nt) {
        int nodeg = row0 + nodebase + nt * 16 + lm;
        bool ok = nodeg < n;
        float dv = ok ? dinv[nodeg] : 0.f;
        #pragma unroll
        for (int ct = 0; ct < 4; ++ct) {
            f32x4 a = acc[ct][nt];
            int ch0 = chbase + ct * 16 + lq * 4;
            if (ok) {
                uint2 pk;
                pk.x = pack_bf16_rne(a[0] * dv, a[1] * dv);
                pk.y = pack_bf16_rne(a[2] * dv, a[3] * dv);
                *(uint2*)&y[(size_t)nodeg * (NCH / 2) + (ch0 >> 1)] = pk;
            }
        }
    }
}

// ---------------- fused gather + combine (+bias, BN stats) ----------------

template<int CH, bool STATS>
__global__ __launch_bounds__(256) void gather_kernel(
    const int* __restrict__ rowptrL, const int* __restrict__ csrL,
    const int* __restrict__ rowptrN, const int* __restrict__ csrN,
    const u32* __restrict__ yL, const u32* __restrict__ yN,
    const float* __restrict__ dinvL, const float* __restrict__ dinvN,
    const float* __restrict__ bL, const float* __restrict__ bN,
    float* __restrict__ out, int n,
    float* __restrict__ bn_sum, float* __restrict__ bn_sumsq)
{
    constexpr int CHW = CH / 2;
    constexpr int NPB = 256 / CHW;
    const int c  = threadIdx.x % CHW;
    const int ns = threadIdx.x / CHW;
    const float2 blv = ((const float2*)bL)[c];
    const float2 bnv = ((const float2*)bN)[c];
    const float cb0 = blv.x + 0.5f * bnv.x;
    const float cb1 = blv.y + 0.5f * bnv.y;

    float s0 = 0.f, s1 = 0.f, q0 = 0.f, q1 = 0.f;

    for (int node0 = blockIdx.x * NPB; node0 < n; node0 += gridDim.x * NPB) {
        const int node = node0 + ns;
        const bool valid = node < n;
        const int nodec = valid ? node : 0;

        u32 selfL = yL[(size_t)nodec * CHW + c];
        u32 selfN = yN[(size_t)nodec * CHW + c];
        float sL0 = bf16_lo(selfL), sL1 = bf16_hi(selfL);
        float sN0 = bf16_lo(selfN), sN1 = bf16_hi(selfN);

        int jL = rowptrL[nodec], eL2 = rowptrL[nodec + 1];
        int jN = rowptrN[nodec], eN2 = rowptrN[nodec + 1];
        if (!valid) { eL2 = jL; eN2 = jN; }
        if constexpr (CHW == 64) {
            jL  = __builtin_amdgcn_readfirstlane(jL);
            eL2 = __builtin_amdgcn_readfirstlane(eL2);
            jN  = __builtin_amdgcn_readfirstlane(jN);
            eN2 = __builtin_amdgcn_readfirstlane(eN2);
        }
        const int lenL = eL2 - jL;
        const int lenN = eN2 - jN;

        int idxL[8], idxN[8];
        if (lenL > 0) {
            #pragma unroll
            for (int k = 0; k < 8; ++k) idxL[k] = csrL[jL + min(k, lenL - 1)];
        }
        if (lenN > 0) {
            #pragma unroll
            for (int k = 0; k < 8; ++k) idxN[k] = csrN[jN + min(k, lenN - 1)];
        }

        const int mx = max(lenL, lenN);
        for (int base = 0; base < mx; base += 8) {
            const bool doL = base < lenL;
            const bool doN = base < lenN;
            u32 aL[8], aN[8];
            if (doL) {
                #pragma unroll
                for (int k = 0; k < 8; ++k) aL[k] = yL[(size_t)idxL[k] * CHW + c];
            }
            if (doN) {
                #pragma unroll
                for (int k = 0; k < 8; ++k) aN[k] = yN[(size_t)idxN[k] * CHW + c];
            }
            if (doL && base + 8 < lenL) {
                #pragma unroll
                for (int k = 0; k < 8; ++k) idxL[k] = csrL[jL + min(base + 8 + k, lenL - 1)];
            }
            if (doN && base + 8 < lenN) {
                #pragma unroll
                for (int k = 0; k < 8; ++k) idxN[k] = csrN[jN + min(base + 8 + k, lenN - 1)];
            }
            if (doL) {
                #pragma unroll
                for (int k = 0; k < 8; ++k) {
                    float m = (base + k < lenL) ? 1.0f : 0.0f;
                    sL0 = fmaf(m, bf16_lo(aL[k]), sL0);
                    sL1 = fmaf(m, bf16_hi(aL[k]), sL1);
                }
            }
            if (doN) {
                #pragma unroll
                for (int k = 0; k < 8; ++k) {
                    float m = (base + k < lenN) ? 1.0f : 0.0f;
                    sN0 = fmaf(m, bf16_lo(aN[k]), sN0);
                    sN1 = fmaf(m, bf16_hi(aN[k]), sN1);
                }
            }
        }

        if (valid) {
            float dl = dinvL[node], dn = 0.5f * dinvN[node];
            float v0 = dl * sL0 + dn * sN0 + cb0;
            float v1 = dl * sL1 + dn * sN1 + cb1;
            ((float2*)out)[(size_t)node * CHW + c] = make_float2(v0, v1);
            if constexpr (STATS) { s0 += v0; s1 += v1; q0 += v0 * v0; q1 += v1 * v1; }
        }
    }

    if constexpr (STATS) {
        __shared__ float4 ls[256];
        ls[threadIdx.x] = make_float4(s0, s1, q0, q1);
        __syncthreads();
        if (threadIdx.x < CHW) {
            float4 a = ls[threadIdx.x];
            #pragma unroll
            for (int i = 1; i < NPB; ++i) {
                float4 b = ls[threadIdx.x + i * CHW];
                a.x += b.x; a.y += b.y; a.z += b.z; a.w += b.w;
            }
            atomicAdd(&bn_sum[2 * threadIdx.x + 0], a.x);
            atomicAdd(&bn_sum[2 * threadIdx.x + 1], a.y);
            atomicAdd(&bn_sumsq[2 * threadIdx.x + 0], a.z);
            atomicAdd(&bn_sumsq[2 * threadIdx.x + 1], a.w);
        }
    }
}

__global__ void bn_final_kernel(
    const float* __restrict__ sum, const float* __restrict__ sumsq,
    const float* __restrict__ gamma, const float* __restrict__ beta,
    float* __restrict__ scale, float* __restrict__ shift, float inv_n)
{
    int c = threadIdx.x;
    float mean = sum[c] * inv_n;
    float var  = sumsq[c] * inv_n - mean * mean;
    float sc = gamma[c] * rsqrtf(var + 1e-5f);
    scale[c] = sc;
    shift[c] = beta[c] - mean * sc;
}

// ---------------- launch ----------------

extern "C" void kernel_launch(void* const* d_in, const int* in_sizes, int n_in,
                              void* d_out, int out_size, void* d_ws, size_t ws_size,
                              hipStream_t stream)
{
    const float* x     = (const float*)d_in[0];
    const int*   adjL  = (const int*)d_in[1];   // adj_low
    const int*   adjN  = (const int*)d_in[3];   // adj_nd_low
    const float* W1L   = (const float*)d_in[5];
    const float* b1L   = (const float*)d_in[6];
    const float* W1N   = (const float*)d_in[7];
    const float* b1N   = (const float*)d_in[8];
    const float* gamma = (const float*)d_in[9];
    const float* beta  = (const float*)d_in[10];
    const float* W2L   = (const float*)d_in[11];
    const float* b2L   = (const float*)d_in[12];
    const float* W2N   = (const float*)d_in[13];
    const float* b2N   = (const float*)d_in[14];

    const int n  = in_sizes[0] / 128;
    const int eL = in_sizes[1] / 2;
    const int eN = in_sizes[3] / 2;
    const int* rowL = adjL;  const int* colL = adjL + eL;
    const int* rowN = adjN;  const int* colN = adjN + eN;
    const int nb = idiv_up(n, BW);

    char* p = (char*)d_ws;
    const size_t ybytes = (size_t)n * 128 * sizeof(short);
    u32* y1L = (u32*)p; p += ybytes;
    u32* y1N = (u32*)p; p += ybytes;
    float* h = (float*)p; p += (size_t)n * 128 * sizeof(float);
    float* dinvL = (float*)p; p += (size_t)n * sizeof(float);
    float* dinvN = (float*)p; p += (size_t)n * sizeof(float);
    float* bn_sum   = (float*)p; p += 128 * sizeof(float);
    float* bn_sumsq = (float*)p; p += 128 * sizeof(float);
    float* bn_scale = (float*)p; p += 128 * sizeof(float);
    float* bn_shift = (float*)p; p += 128 * sizeof(float);
    int* degL    = (int*)p; p += (size_t)n * sizeof(int);
    int* degN    = (int*)p; p += (size_t)n * sizeof(int);
    int* rowptrL = (int*)p; p += (size_t)(n + 1) * sizeof(int);
    int* rowptrN = (int*)p; p += (size_t)(n + 1) * sizeof(int);
    int* gcurL   = (int*)p; p += 64 * sizeof(int);
    int* gcurN   = (int*)p; p += 64 * sizeof(int);
    int* csrL    = (int*)p; p += (size_t)eL * sizeof(int);
    int* csrN    = (int*)p; p += (size_t)eN * sizeof(int);
    u16* WtL1 = (u16*)p; p += 128 * 128 * sizeof(u16);
    u16* WtN1 = (u16*)p; p += 128 * 128 * sizeof(u16);
    u16* WtL2 = (u16*)p; p += 64 * 128 * sizeof(u16);
    u16* WtN2 = (u16*)p; p += 64 * 128 * sizeof(u16);

    // staging aliases h (dead until gather1, which runs after binB)
    uint2* stagedL = (uint2*)h;
    uint2* stagedN = stagedL + eL;

    // layer-2 y tables reuse y1L space
    u32* y2L = y1L;
    u32* y2N = y1L + (size_t)n * 32;

    hipMemsetAsync(degL, 0, (size_t)n * 2 * sizeof(int), stream);
    hipMemsetAsync(bn_sum, 0, 2 * 128 * sizeof(float), stream);

    wprep_kernel<<<dim3(64, 4), 256, 0, stream>>>(
        W1L, W1N, W2L, W2N, WtL1, WtN1, WtL2, WtN2);

    const int emax = eL > eN ? eL : eN;
    count_deg_kernel<<<idiv_up(emax, 256), 256, 0, stream>>>(colL, colN, eL, eN, degL, degN);
    dinv_kernel<<<idiv_up(n, 256), 256, 0, stream>>>(degL, degN, dinvL, dinvN, n);
    scan_kernel<<<2, 1024, 0, stream>>>(degL, degN, n, rowptrL, rowptrN);
    init_gcur_kernel<<<1, 64, 0, stream>>>(rowptrL, rowptrN, gcurL, gcurN, nb);

    binA_kernel<<<dim3(idiv_up(emax, ACHUNK), 2), 256, 0, stream>>>(
        rowL, colL, eL, rowN, colN, eN, gcurL, gcurN, stagedL, stagedN, nb);
    binB_kernel<<<dim3(nb, 2), 256, 0, stream>>>(
        rowptrL, rowptrN, stagedL, stagedN, csrL, csrN, n);

    // layer 1 (MFMA, both streams per block)
    mfma_gemm_kernel<128, false><<<idiv_up(n, 64), 256, 0, stream>>>(
        x, n, WtL1, WtN1, dinvL, dinvN, y1L, y1N, nullptr, nullptr);

    gather_kernel<128, true><<<4096, 256, 0, stream>>>(
        rowptrL, csrL, rowptrN, csrN, y1L, y1N, dinvL, dinvN,
        b1L, b1N, h, n, bn_sum, bn_sumsq);

    bn_final_kernel<<<1, 128, 0, stream>>>(bn_sum, bn_sumsq, gamma, beta,
                                           bn_scale, bn_shift, 1.0f / (float)n);

    // layer 2 (MFMA, BN+ReLU fused into A staging)
    mfma_gemm_kernel<64, true><<<idiv_up(n, 64), 256, 0, stream>>>(
        h, n, WtL2, WtN2, dinvL, dinvN, y2L, y2N, bn_scale, bn_shift);

    gather_kernel<64, false><<<4096, 256, 0, stream>>>(
        rowptrL, csrL, rowptrN, csrN, y2L, y2N, dinvL, dinvN,
        b2L, b2N, (float*)d_out, n, nullptr, nullptr);
}

// Round 11
// 780.526 us; speedup vs baseline: 1.1376x; 1.0261x over previous
//
#include <hip/hip_runtime.h>

typedef unsigned int u32;
typedef unsigned short u16;
using bf16x8 = __attribute__((ext_vector_type(8))) short;
using f32x4  = __attribute__((ext_vector_type(4))) float;

static inline int idiv_up(int a, int b) { return (a + b - 1) / b; }

#define BSHIFT 11          // bucket width 2048 nodes
#define BW     2048
#define ACHUNK 8192        // edges per binA block

// ---------------- bf16 pack/unpack ----------------

__device__ __forceinline__ u32 pack_bf16_rne(float lo, float hi) {
    u32 ul = __float_as_uint(lo);
    u32 uh = __float_as_uint(hi);
    ul = (ul + 0x7fffu + ((ul >> 16) & 1u)) >> 16;
    uh = (uh + 0x7fffu + ((uh >> 16) & 1u));
    return (ul & 0xffffu) | (uh & 0xffff0000u);
}
__device__ __forceinline__ u16 bf16_rne1(float v) {
    u32 u = __float_as_uint(v);
    return (u16)((u + 0x7fffu + ((u >> 16) & 1u)) >> 16);
}
__device__ __forceinline__ float bf16_lo(u32 u) { return __uint_as_float(u << 16); }
__device__ __forceinline__ float bf16_hi(u32 u) { return __uint_as_float(u & 0xffff0000u); }

// ---------------- fused: count_deg (int4) ∥ wprep ----------------

__global__ __launch_bounds__(256) void prep_kernel(
    const int* __restrict__ colL, const int* __restrict__ colN,
    int eL, int eN,
    int* __restrict__ degL, int* __restrict__ degN,
    const float* __restrict__ W1L, const float* __restrict__ W1N,
    const float* __restrict__ W2L, const float* __restrict__ W2N,
    u16* __restrict__ T1L, u16* __restrict__ T1N,
    u16* __restrict__ T2L, u16* __restrict__ T2N,
    int nCount)
{
    const int t = threadIdx.x;
    if ((int)blockIdx.x < nCount) {
        int i4 = blockIdx.x * 256 + t;
        if (i4 < (eL >> 2)) {
            int4 c = ((const int4*)colL)[i4];
            atomicAdd(&degL[c.x], 1); atomicAdd(&degL[c.y], 1);
            atomicAdd(&degL[c.z], 1); atomicAdd(&degL[c.w], 1);
        }
        if (i4 < (eN >> 2)) {
            int4 c = ((const int4*)colN)[i4];
            atomicAdd(&degN[c.x], 1); atomicAdd(&degN[c.y], 1);
            atomicAdd(&degN[c.z], 1); atomicAdd(&degN[c.w], 1);
        }
        if (blockIdx.x == 0) {
            if (t < (eL & 3)) atomicAdd(&degL[colL[(eL & ~3) + t]], 1);
            if (t < (eN & 3)) atomicAdd(&degN[colN[(eN & ~3) + t]], 1);
        }
    } else {
        int b = blockIdx.x - nCount;          // 0..255
        int which = b >> 6, bx = b & 63;
        const float* src = which == 0 ? W1L : which == 1 ? W1N : which == 2 ? W2L : W2N;
        u16* dst         = which == 0 ? T1L : which == 1 ? T1N : which == 2 ? T2L : T2N;
        const int nc = which < 2 ? 128 : 64;
        int i = bx * 256 + t;
        if (i < 128 * nc) {
            int k = i / nc, nn = i % nc;
            dst[nn * 128 + k] = bf16_rne1(src[i]);
        }
    }
}

// ---------------- fused: scan(+gcur emission) ∥ dinv ----------------

__global__ __launch_bounds__(1024) void scan_dinv_kernel(
    const int* __restrict__ degL, const int* __restrict__ degN, int n,
    int* __restrict__ rowptrL, int* __restrict__ rowptrN,
    int* __restrict__ gcurL, int* __restrict__ gcurN,
    float* __restrict__ dinvL, float* __restrict__ dinvN)
{
    const int t = threadIdx.x;
    if (blockIdx.x < 2) {
        const int* deg = blockIdx.x ? degN : degL;
        int* rowptr    = blockIdx.x ? rowptrN : rowptrL;
        int* gcur      = blockIdx.x ? gcurN : gcurL;

        __shared__ int ls[1024];
        const int chunk = (n + 1023) / 1024;
        const int base = t * chunk;

        int s = 0;
        for (int i = 0; i < chunk; ++i) {
            int idx = base + i;
            if (idx < n) s += deg[idx];
        }
        ls[t] = s;
        __syncthreads();
        for (int off = 1; off < 1024; off <<= 1) {
            int add = (t >= off) ? ls[t - off] : 0;
            __syncthreads();
            ls[t] += add;
            __syncthreads();
        }
        int running = (t == 0) ? 0 : ls[t - 1];
        int total = ls[1023];
        for (int i = 0; i < chunk; ++i) {
            int idx = base + i;
            if (idx < n) {
                rowptr[idx] = running;
                if ((idx & (BW - 1)) == 0) gcur[idx >> BSHIFT] = running;
                running += deg[idx];
            }
        }
        if (t == 1023) rowptr[n] = total;
    } else {
        int i = (blockIdx.x - 2) * 1024 + t;
        if (i < n) {
            dinvL[i] = rsqrtf((float)degL[i] + 1.0f);   // +1 self loop
            dinvN[i] = rsqrtf((float)degN[i] + 1.0f);
        }
    }
}

// ---------------- MFMA GEMM body (device fn) ----------------
// A fp32 [n][128] (optional BN+ReLU on load), Wt bf16 [NCH][128].
// Wt = MFMA A-operand, x = B-operand: lane holds 4 consecutive output
// channels of one node. LDS A tile XOR-swizzled byte^=(r&7)<<4.

template<int NCH, bool BN>
__device__ __forceinline__ void mfma_gemm_body(
    int gb, const float* __restrict__ A, int n,
    const u16* __restrict__ WtL, const u16* __restrict__ WtN,
    const float* __restrict__ dinvL, const float* __restrict__ dinvN,
    u32* __restrict__ yL, u32* __restrict__ yN,
    const float* bn_scale, const float* bn_shift)
{
    constexpr int NT = (NCH == 128) ? 4 : 2;
    __shared__ u16 lsa[64 * 128];

    const int row0 = gb * 64;
    const int t = threadIdx.x;
    const int l = t & 63;
    const int w = t >> 6;

    const float4* A4 = (const float4*)A;
    #pragma unroll
    for (int i = 0; i < 8; ++i) {
        int q = i * 256 + t;
        int r = q >> 5, c4 = q & 31;
        int rr = row0 + r;
        float4 v = make_float4(0.f, 0.f, 0.f, 0.f);
        if (rr < n) v = A4[(size_t)rr * 32 + c4];
        if constexpr (BN) {
            float4 sc = ((const float4*)bn_scale)[c4];
            float4 sh = ((const float4*)bn_shift)[c4];
            v.x = fmaxf(v.x * sc.x + sh.x, 0.f);
            v.y = fmaxf(v.y * sc.y + sh.y, 0.f);
            v.z = fmaxf(v.z * sc.z + sh.z, 0.f);
            v.w = fmaxf(v.w * sc.w + sh.w, 0.f);
        }
        int byte = (r * 256 + c4 * 8) ^ ((r & 7) << 4);
        *(uint2*)((char*)lsa + byte) = make_uint2(pack_bf16_rne(v.x, v.y),
                                                 pack_bf16_rne(v.z, v.w));
    }
    __syncthreads();

    const int stream = w >> 1;
    const int chbase   = (NCH == 128) ? (w & 1) * 64 : 0;
    const int nodebase = (NCH == 128) ? 0 : (w & 1) * 32;
    const u16* Wt      = stream ? WtN : WtL;
    const float* dinv  = stream ? dinvN : dinvL;
    u32* y             = stream ? yN : yL;

    f32x4 acc[4][NT];
    #pragma unroll
    for (int ct = 0; ct < 4; ++ct)
        #pragma unroll
        for (int nt = 0; nt < NT; ++nt)
            acc[ct][nt] = (f32x4){0.f, 0.f, 0.f, 0.f};

    const int lm = l & 15;
    const int lq = l >> 4;

    #pragma unroll
    for (int ks = 0; ks < 4; ++ks) {
        const int k0 = ks * 32 + lq * 8;
        bf16x8 wf[4];
        #pragma unroll
        for (int ct = 0; ct < 4; ++ct) {
            int nch = chbase + ct * 16 + lm;
            wf[ct] = *(const bf16x8*)&Wt[(size_t)nch * 128 + k0];
        }
        #pragma unroll
        for (int nt = 0; nt < NT; ++nt) {
            int m = nodebase + nt * 16 + lm;
            int byte = (m * 256 + k0 * 2) ^ ((m & 7) << 4);
            bf16x8 xf = *(const bf16x8*)((const char*)lsa + byte);
            #pragma unroll
            for (int ct = 0; ct < 4; ++ct)
                acc[ct][nt] = __builtin_amdgcn_mfma_f32_16x16x32_bf16(
                    wf[ct], xf, acc[ct][nt], 0, 0, 0);
        }
    }

    #pragma unroll
    for (int nt = 0; nt < NT; ++nt) {
        int nodeg = row0 + nodebase + nt * 16 + lm;
        bool ok = nodeg < n;
        float dv = ok ? dinv[nodeg] : 0.f;
        #pragma unroll
        for (int ct = 0; ct < 4; ++ct) {
            f32x4 a = acc[ct][nt];
            int ch0 = chbase + ct * 16 + lq * 4;
            if (ok) {
                uint2 pk;
                pk.x = pack_bf16_rne(a[0] * dv, a[1] * dv);
                pk.y = pack_bf16_rne(a[2] * dv, a[3] * dv);
                *(uint2*)&y[(size_t)nodeg * (NCH / 2) + (ch0 >> 1)] = pk;
            }
        }
    }
}

// ---------------- fused: binA ∥ GEMM1 ----------------

__global__ __launch_bounds__(256) void binA_gemm1_kernel(
    const int* __restrict__ rowL, const int* __restrict__ colL, int eL,
    const int* __restrict__ rowN, const int* __restrict__ colN, int eN,
    int* __restrict__ gcurL, int* __restrict__ gcurN,
    uint2* __restrict__ stagedL, uint2* __restrict__ stagedN, int nb, int nA,
    const float* __restrict__ x, int n,
    const u16* __restrict__ WtL1, const u16* __restrict__ WtN1,
    const float* __restrict__ dinvL, const float* __restrict__ dinvN,
    u32* __restrict__ y1L, u32* __restrict__ y1N)
{
    const int t = threadIdx.x;
    if ((int)blockIdx.x < 2 * nA) {
        const int adj = (int)blockIdx.x >= nA;
        const int chunkb = adj ? blockIdx.x - nA : blockIdx.x;
        const int* rowA = adj ? rowN : rowL;
        const int* colA = adj ? colN : colL;
        const int e     = adj ? eN   : eL;
        int* gcur       = adj ? gcurN : gcurL;
        uint2* staged   = adj ? stagedN : stagedL;

        __shared__ int hist[64];
        __shared__ int base[64];
        if (t < 64) hist[t] = 0;
        __syncthreads();

        const int i0 = chunkb * ACHUNK;
        const int i1 = min(i0 + ACHUNK, e);

        for (int i = i0 + t; i < i1; i += 256)
            atomicAdd(&hist[colA[i] >> BSHIFT], 1);
        __syncthreads();

        if (t < 64) {
            int cnt = hist[t];
            if (t < nb && cnt > 0) base[t] = atomicAdd(&gcur[t], cnt);
        }
        __syncthreads();
        if (t < 64) hist[t] = 0;
        __syncthreads();

        for (int i = i0 + t; i < i1; i += 256) {
            int c = colA[i], r = rowA[i];
            int b = c >> BSHIFT;
            int pos = base[b] + atomicAdd(&hist[b], 1);
            staged[pos] = make_uint2((u32)c, (u32)r);
        }
    } else {
        int gb = blockIdx.x - 2 * nA;
        mfma_gemm_body<128, false>(gb, x, n, WtL1, WtN1, dinvL, dinvN,
                                   y1L, y1N, nullptr, nullptr);
    }
}

// ---------------- radix pass B ----------------

__global__ __launch_bounds__(256) void binB_kernel(
    const int* __restrict__ rowptrL, const int* __restrict__ rowptrN,
    const uint2* __restrict__ stagedL, const uint2* __restrict__ stagedN,
    int* __restrict__ csrL, int* __restrict__ csrN, int n)
{
    const int adj = blockIdx.y;
    const int* rowptr   = adj ? rowptrN : rowptrL;
    const uint2* staged = adj ? stagedN : stagedL;
    int* csr            = adj ? csrN    : csrL;

    __shared__ int lcur[BW];
    const int lo = blockIdx.x << BSHIFT;
    const int hi = min(lo + BW, n);
    const int t = threadIdx.x;

    for (int i = lo + t; i < hi; i += 256) lcur[i - lo] = rowptr[i];
    __syncthreads();

    const int s0 = rowptr[lo], s1 = rowptr[hi];
    for (int i = s0 + t; i < s1; i += 256) {
        uint2 er = staged[i];
        int p = atomicAdd(&lcur[(int)er.x - lo], 1);
        csr[p] = (int)er.y;
    }
}

// ---------------- GEMM2: in-kernel BN finalize + MFMA body ----------------

__global__ __launch_bounds__(256) void gemm2_kernel(
    const float* __restrict__ h, int n,
    const u16* __restrict__ WtL2, const u16* __restrict__ WtN2,
    const float* __restrict__ dinvL, const float* __restrict__ dinvN,
    u32* __restrict__ y2L, u32* __restrict__ y2N,
    const float* __restrict__ bn_sum, const float* __restrict__ bn_sumsq,
    const float* __restrict__ gamma, const float* __restrict__ beta,
    float inv_n)
{
    __shared__ float sc_s[128], sh_s[128];
    const int t = threadIdx.x;
    if (t < 128) {
        float mean = bn_sum[t] * inv_n;
        float var  = bn_sumsq[t] * inv_n - mean * mean;
        float sc = gamma[t] * rsqrtf(var + 1e-5f);
        sc_s[t] = sc;
        sh_s[t] = beta[t] - mean * sc;
    }
    __syncthreads();
    mfma_gemm_body<64, true>(blockIdx.x, h, n, WtL2, WtN2, dinvL, dinvN,
                             y2L, y2N, sc_s, sh_s);
}

// ---------------- fused gather + combine (+bias, BN stats) ----------------

template<int CH, bool STATS>
__global__ __launch_bounds__(256) void gather_kernel(
    const int* __restrict__ rowptrL, const int* __restrict__ csrL,
    const int* __restrict__ rowptrN, const int* __restrict__ csrN,
    const u32* __restrict__ yL, const u32* __restrict__ yN,
    const float* __restrict__ dinvL, const float* __restrict__ dinvN,
    const float* __restrict__ bL, const float* __restrict__ bN,
    float* __restrict__ out, int n,
    float* __restrict__ bn_sum, float* __restrict__ bn_sumsq)
{
    constexpr int CHW = CH / 2;
    constexpr int NPB = 256 / CHW;
    const int c  = threadIdx.x % CHW;
    const int ns = threadIdx.x / CHW;
    const float2 blv = ((const float2*)bL)[c];
    const float2 bnv = ((const float2*)bN)[c];
    const float cb0 = blv.x + 0.5f * bnv.x;
    const float cb1 = blv.y + 0.5f * bnv.y;

    float s0 = 0.f, s1 = 0.f, q0 = 0.f, q1 = 0.f;

    for (int node0 = blockIdx.x * NPB; node0 < n; node0 += gridDim.x * NPB) {
        const int node = node0 + ns;
        const bool valid = node < n;
        const int nodec = valid ? node : 0;

        u32 selfL = yL[(size_t)nodec * CHW + c];
        u32 selfN = yN[(size_t)nodec * CHW + c];
        float sL0 = bf16_lo(selfL), sL1 = bf16_hi(selfL);
        float sN0 = bf16_lo(selfN), sN1 = bf16_hi(selfN);

        int jL = rowptrL[nodec], eL2 = rowptrL[nodec + 1];
        int jN = rowptrN[nodec], eN2 = rowptrN[nodec + 1];
        if (!valid) { eL2 = jL; eN2 = jN; }
        if constexpr (CHW == 64) {
            jL  = __builtin_amdgcn_readfirstlane(jL);
            eL2 = __builtin_amdgcn_readfirstlane(eL2);
            jN  = __builtin_amdgcn_readfirstlane(jN);
            eN2 = __builtin_amdgcn_readfirstlane(eN2);
        }
        const int lenL = eL2 - jL;
        const int lenN = eN2 - jN;

        int idxL[8], idxN[8];
        if (lenL > 0) {
            #pragma unroll
            for (int k = 0; k < 8; ++k) idxL[k] = csrL[jL + min(k, lenL - 1)];
        }
        if (lenN > 0) {
            #pragma unroll
            for (int k = 0; k < 8; ++k) idxN[k] = csrN[jN + min(k, lenN - 1)];
        }

        const int mx = max(lenL, lenN);
        for (int base = 0; base < mx; base += 8) {
            const bool doL = base < lenL;
            const bool doN = base < lenN;
            u32 aL[8], aN[8];
            if (doL) {
                #pragma unroll
                for (int k = 0; k < 8; ++k) aL[k] = yL[(size_t)idxL[k] * CHW + c];
            }
            if (doN) {
                #pragma unroll
                for (int k = 0; k < 8; ++k) aN[k] = yN[(size_t)idxN[k] * CHW + c];
            }
            if (doL && base + 8 < lenL) {
                #pragma unroll
                for (int k = 0; k < 8; ++k) idxL[k] = csrL[jL + min(base + 8 + k, lenL - 1)];
            }
            if (doN && base + 8 < lenN) {
                #pragma unroll
                for (int k = 0; k < 8; ++k) idxN[k] = csrN[jN + min(base + 8 + k, lenN - 1)];
            }
            if (doL) {
                #pragma unroll
                for (int k = 0; k < 8; ++k) {
                    float m = (base + k < lenL) ? 1.0f : 0.0f;
                    sL0 = fmaf(m, bf16_lo(aL[k]), sL0);
                    sL1 = fmaf(m, bf16_hi(aL[k]), sL1);
                }
            }
            if (doN) {
                #pragma unroll
                for (int k = 0; k < 8; ++k) {
                    float m = (base + k < lenN) ? 1.0f : 0.0f;
                    sN0 = fmaf(m, bf16_lo(aN[k]), sN0);
                    sN1 = fmaf(m, bf16_hi(aN[k]), sN1);
                }
            }
        }

        if (valid) {
            float dl = dinvL[node], dn = 0.5f * dinvN[node];
            float v0 = dl * sL0 + dn * sN0 + cb0;
            float v1 = dl * sL1 + dn * sN1 + cb1;
            ((float2*)out)[(size_t)node * CHW + c] = make_float2(v0, v1);
            if constexpr (STATS) { s0 += v0; s1 += v1; q0 += v0 * v0; q1 += v1 * v1; }
        }
    }

    if constexpr (STATS) {
        __shared__ float4 ls[256];
        ls[threadIdx.x] = make_float4(s0, s1, q0, q1);
        __syncthreads();
        if (threadIdx.x < CHW) {
            float4 a = ls[threadIdx.x];
            #pragma unroll
            for (int i = 1; i < NPB; ++i) {
                float4 b = ls[threadIdx.x + i * CHW];
                a.x += b.x; a.y += b.y; a.z += b.z; a.w += b.w;
            }
            atomicAdd(&bn_sum[2 * threadIdx.x + 0], a.x);
            atomicAdd(&bn_sum[2 * threadIdx.x + 1], a.y);
            atomicAdd(&bn_sumsq[2 * threadIdx.x + 0], a.z);
            atomicAdd(&bn_sumsq[2 * threadIdx.x + 1], a.w);
        }
    }
}

// ---------------- launch ----------------

extern "C" void kernel_launch(void* const* d_in, const int* in_sizes, int n_in,
                              void* d_out, int out_size, void* d_ws, size_t ws_size,
                              hipStream_t stream)
{
    const float* x     = (const float*)d_in[0];
    const int*   adjL  = (const int*)d_in[1];   // adj_low
    const int*   adjN  = (const int*)d_in[3];   // adj_nd_low
    const float* W1L   = (const float*)d_in[5];
    const float* b1L   = (const float*)d_in[6];
    const float* W1N   = (const float*)d_in[7];
    const float* b1N   = (const float*)d_in[8];
    const float* gamma = (const float*)d_in[9];
    const float* beta  = (const float*)d_in[10];
    const float* W2L   = (const float*)d_in[11];
    const float* b2L   = (const float*)d_in[12];
    const float* W2N   = (const float*)d_in[13];
    const float* b2N   = (const float*)d_in[14];

    const int n  = in_sizes[0] / 128;
    const int eL = in_sizes[1] / 2;
    const int eN = in_sizes[3] / 2;
    const int* rowL = adjL;  const int* colL = adjL + eL;
    const int* rowN = adjN;  const int* colN = adjN + eN;
    const int nb = idiv_up(n, BW);

    char* p = (char*)d_ws;
    const size_t ybytes = (size_t)n * 128 * sizeof(short);
    u32* y1L = (u32*)p; p += ybytes;
    u32* y1N = (u32*)p; p += ybytes;
    float* h = (float*)p; p += (size_t)n * 128 * sizeof(float);
    float* dinvL = (float*)p; p += (size_t)n * sizeof(float);
    float* dinvN = (float*)p; p += (size_t)n * sizeof(float);
    float* bn_sum   = (float*)p; p += 128 * sizeof(float);
    float* bn_sumsq = (float*)p; p += 128 * sizeof(float);
    int* degL    = (int*)p; p += (size_t)n * sizeof(int);
    int* degN    = (int*)p; p += (size_t)n * sizeof(int);
    int* rowptrL = (int*)p; p += (size_t)(n + 1) * sizeof(int);
    int* rowptrN = (int*)p; p += (size_t)(n + 1) * sizeof(int);
    int* gcurL   = (int*)p; p += 64 * sizeof(int);
    int* gcurN   = (int*)p; p += 64 * sizeof(int);
    int* csrL    = (int*)p; p += (size_t)eL * sizeof(int);
    int* csrN    = (int*)p; p += (size_t)eN * sizeof(int);
    u16* WtL1 = (u16*)p; p += 128 * 128 * sizeof(u16);
    u16* WtN1 = (u16*)p; p += 128 * 128 * sizeof(u16);
    u16* WtL2 = (u16*)p; p += 64 * 128 * sizeof(u16);
    u16* WtN2 = (u16*)p; p += 64 * 128 * sizeof(u16);

    // staging aliases h (dead until gather1, which runs after binB)
    uint2* stagedL = (uint2*)h;
    uint2* stagedN = stagedL + eL;

    // layer-2 y tables reuse y1L space
    u32* y2L = y1L;
    u32* y2N = y1L + (size_t)n * 32;

    hipMemsetAsync(degL, 0, (size_t)n * 2 * sizeof(int), stream);
    hipMemsetAsync(bn_sum, 0, 2 * 128 * sizeof(float), stream);

    const int emax = eL > eN ? eL : eN;

    // 1. count_deg (int4) ∥ wprep
    const int nCount = idiv_up(emax >> 2, 256);
    prep_kernel<<<nCount + 256, 256, 0, stream>>>(
        colL, colN, eL, eN, degL, degN,
        W1L, W1N, W2L, W2N, WtL1, WtN1, WtL2, WtN2, nCount);

    // 2. scan (+gcur) ∥ dinv
    scan_dinv_kernel<<<2 + idiv_up(n, 1024), 1024, 0, stream>>>(
        degL, degN, n, rowptrL, rowptrN, gcurL, gcurN, dinvL, dinvN);

    // 3. binA ∥ GEMM1
    const int nA = idiv_up(emax, ACHUNK);
    binA_gemm1_kernel<<<2 * nA + idiv_up(n, 64), 256, 0, stream>>>(
        rowL, colL, eL, rowN, colN, eN, gcurL, gcurN, stagedL, stagedN, nb, nA,
        x, n, WtL1, WtN1, dinvL, dinvN, y1L, y1N);

    // 4. binB
    binB_kernel<<<dim3(nb, 2), 256, 0, stream>>>(
        rowptrL, rowptrN, stagedL, stagedN, csrL, csrN, n);

    // 5. gather1 (+BN stats)
    gather_kernel<128, true><<<4096, 256, 0, stream>>>(
        rowptrL, csrL, rowptrN, csrN, y1L, y1N, dinvL, dinvN,
        b1L, b1N, h, n, bn_sum, bn_sumsq);

    // 6. GEMM2 (in-kernel BN finalize, BN+ReLU fused into A staging)
    gemm2_kernel<<<idiv_up(n, 64), 256, 0, stream>>>(
        h, n, WtL2, WtN2, dinvL, dinvN, y2L, y2N,
        bn_sum, bn_sumsq, gamma, beta, 1.0f / (float)n);

    // 7. gather2
    gather_kernel<64, false><<<4096, 256, 0, stream>>>(
        rowptrL, csrL, rowptrN, csrN, y2L, y2N, dinvL, dinvN,
        b2L, b2N, (float*)d_out, n, nullptr, nullptr);
}